// Round 1
// 69.962 us; speedup vs baseline: 1.0189x; 1.0189x over previous
//
#include <hip/hip_runtime.h>
#include <math.h>

// Problem constants (from reference setup_inputs)
constexpr int BS = 16;
constexpr int NQ = 100;
constexpr int JD = 51;
constexpr int NA = 8;    // action classes
constexpr int NI = 10;   // identity classes
constexpr int ITILE = 4;             // i-rows per block
constexpr int NTILES = NQ / ITILE;   // 25
constexpr int BLOCK = 256;

// out[b,i,j] = -(t_j*log(p_i) + (1-t_j)*log(1-p_i))            (C_prob)
//            + sum_k |pred_joint[b,i,k] - tar_joint[b,j,k]|     (C_joint)
//            + CE(pred_action[b,i])[0] + CE(pred_identity[b,i])[0]
//
// Identity used for C_prob fold:  log(p)-log(1-p) = x  (the logit), so
//   C_prob = -(t*lp + (1-t)*l1p) = -l1p - t*x
//   out    = (rowc - l1p) - t*x + s   ->  fmaf(-t, x, c0) + s
//
// v2: tar_joint rows are read straight from global into registers.
// tar_joint is 326 KB total (20.4 KB per b, re-read by 25 blocks) -> fully
// L1/L2-resident; the previous 20.4 KB global->LDS->reg round trip + barrier
// drain was pure latency overhead (guide: don't LDS-stage L2-fit data).
__global__ __launch_bounds__(BLOCK) void matcher_kernel(
    const float* __restrict__ pred_conf,    // [BS,NQ,1]
    const float* __restrict__ pred_joint,   // [BS,NQ,JD]
    const float* __restrict__ pred_action,  // [BS,NQ,NA]
    const float* __restrict__ pred_ident,   // [BS,NQ,NI]
    const float* __restrict__ tar_conf,     // [BS,NQ]
    const float* __restrict__ tar_joint,    // [BS,NQ,JD]
    float* __restrict__ out)                // [BS,NQ,NQ]
{
    const int b   = blockIdx.x;
    const int i0  = blockIdx.y * ITILE;
    const int tid = threadIdx.x;

    // Tiny LDS only: 4 pred_joint rows (816 B) + 2*ITILE scalars.
    __shared__ __align__(16) float pjs[ITILE * JD];
    __shared__ float c0s[ITILE];   // (ce_a + ce_i) - log(1-p_i)
    __shared__ float xs[ITILE];    // conf logit x_i

    const int j  = tid & 127;      // 0..127 (j < NQ active)
    const int ih = tid >> 7;       // 0/1 -> which half of the i-tile

    // --- per-thread target row -> registers, direct from global (L1/L2 hit).
    // Issued first so the ~200-cycle cache latency hides under the staging
    // and row-term work below.
    float tj[JD];
    float t = 0.f;
    if (j < NQ) {
        const float* tjp = tar_joint + ((size_t)b * NQ + j) * JD;
        #pragma unroll
        for (int k = 0; k < JD; k++) tj[k] = tjp[k];
        t = tar_conf[b * NQ + j];
    }

    // --- wave 0: stage the 4 pred_joint rows via float4
    //     (base byte offset = 816*(25*b + blockIdx.y), multiple of 16)
    if (tid < (ITILE * JD) / 4) {   // 51 vec4
        const float4* pj4 = (const float4*)(pred_joint + ((size_t)b * NQ + i0) * JD);
        ((float4*)pjs)[tid] = pj4[tid];
    }

    // --- wave 1: per-i row scalar terms (overlaps wave 0's staging)
    if (tid >= 64 && tid < 64 + ITILE) {
        const int il  = tid - 64;
        const int row = b * NQ + i0 + il;
        const float x = pred_conf[row];
        // log(sigmoid(x)) = -log1p(exp(-x)); log(1-sigmoid(x)) = that - x
        const float lp  = -log1pf(__expf(-x));
        const float l1p = lp - x;

        const float* a = pred_action + (size_t)row * NA;
        float m = a[0];
        #pragma unroll
        for (int k = 1; k < NA; k++) m = fmaxf(m, a[k]);
        float s = 0.f;
        #pragma unroll
        for (int k = 0; k < NA; k++) s += __expf(a[k] - m);
        const float cea = __logf(s) + m - a[0];

        const float* pi = pred_ident + (size_t)row * NI;
        float m2 = pi[0];
        #pragma unroll
        for (int k = 1; k < NI; k++) m2 = fmaxf(m2, pi[k]);
        float s2 = 0.f;
        #pragma unroll
        for (int k = 0; k < NI; k++) s2 += __expf(pi[k] - m2);
        const float cei = __logf(s2) + m2 - pi[0];

        c0s[il] = (cea + cei) - l1p;
        xs[il]  = x;
    }
    __syncthreads();   // only guards 848 B of LDS now

    // --- compute: thread owns column j; two waves split the i-tile
    if (j < NQ) {
        float* outp = out + ((size_t)b * NQ + i0) * NQ + j;
        const int il_beg = ih * (ITILE / 2);
        #pragma unroll
        for (int il = il_beg; il < il_beg + ITILE / 2; il++) {
            // pjs reads are wave-uniform -> LDS broadcast (conflict-free).
            // 4-way split accumulators break the 51-long dependent add chain.
            float s0 = 0.f, s1 = 0.f, s2 = 0.f, s3 = 0.f;
            #pragma unroll
            for (int k = 0; k + 3 < JD; k += 4) {
                s0 += fabsf(pjs[il * JD + k + 0] - tj[k + 0]);
                s1 += fabsf(pjs[il * JD + k + 1] - tj[k + 1]);
                s2 += fabsf(pjs[il * JD + k + 2] - tj[k + 2]);
                s3 += fabsf(pjs[il * JD + k + 3] - tj[k + 3]);
            }
            // JD = 51: 48 handled above, 3 remain
            s0 += fabsf(pjs[il * JD + 48] - tj[48]);
            s1 += fabsf(pjs[il * JD + 49] - tj[49]);
            s2 += fabsf(pjs[il * JD + 50] - tj[50]);
            const float s = (s0 + s1) + (s2 + s3);
            outp[(size_t)il * NQ] = fmaf(-t, xs[il], c0s[il]) + s;
        }
    }
}

extern "C" void kernel_launch(void* const* d_in, const int* in_sizes, int n_in,
                              void* d_out, int out_size, void* d_ws, size_t ws_size,
                              hipStream_t stream) {
    const float* pred_conf   = (const float*)d_in[0];
    const float* pred_joint  = (const float*)d_in[1];
    const float* pred_action = (const float*)d_in[2];
    const float* pred_ident  = (const float*)d_in[3];
    const float* tar_conf    = (const float*)d_in[4];
    const float* tar_joint   = (const float*)d_in[5];
    // d_in[6] (tar_action) and d_in[7] (tar_identity) are unused by the reference cost.
    float* outp = (float*)d_out;

    dim3 grid(BS, NTILES);
    matcher_kernel<<<grid, BLOCK, 0, stream>>>(
        pred_conf, pred_joint, pred_action, pred_ident, tar_conf, tar_joint, outp);
}